// Round 16
// baseline (188.380 us; speedup 1.0000x reference)
//
#include <hip/hip_runtime.h>
#include <hip/hip_bf16.h>
#include <math.h>

#define B_   32
#define CI   256
#define CO   256
#define KW   7
#define NW   8
#define SQD  8
#define L_   4096
#define PITCH 264

typedef __attribute__((ext_vector_type(8))) __bf16 bf16x8;
typedef __attribute__((ext_vector_type(4))) __bf16 bf16x4;
typedef __attribute__((ext_vector_type(4))) float  f32x4;

static __device__ __forceinline__ unsigned short f2bf(float f) {
    unsigned int u = __builtin_bit_cast(unsigned int, f);
    u += 0x7FFFu + ((u >> 16) & 1u);
    return (unsigned short)(u >> 16);
}
// native-cast pack: compiler emits v_cvt_pk_bf16_f32
static __device__ __forceinline__ uint2 pack4bf(float a, float b, float c, float d) {
    bf16x4 v;
    v[0] = (__bf16)a; v[1] = (__bf16)b; v[2] = (__bf16)c; v[3] = (__bf16)d;
    return __builtin_bit_cast(uint2, v);
}

// ---------------------------------------------------------------------------
// k1: mean over L (deterministic). One block per (b,i) row.
// ---------------------------------------------------------------------------
__global__ __launch_bounds__(256) void k1_mean(
        const float* __restrict__ x, float* __restrict__ pooled) {
    int row = blockIdx.x;                       // b*CI + i
    const float* p = x + (size_t)row * L_;
    int t = threadIdx.x;
    float s = 0.f;
#pragma unroll
    for (int it = 0; it < 4; ++it) {
        float4 v = *(const float4*)(p + (size_t)(t + 256 * it) * 4);
        s += v.x + v.y + v.z + v.w;
    }
    for (int m = 1; m <= 32; m <<= 1) s += __shfl_xor(s, m);
    __shared__ float wsum[4];
    if ((t & 63) == 0) wsum[t >> 6] = s;
    __syncthreads();
    if (t == 0)
        pooled[row] = (wsum[0] + wsum[1] + wsum[2] + wsum[3]) * (1.0f / L_);
}

// ---------------------------------------------------------------------------
// k2: squeeze net + gates. one block (1 wave) per sample.
// ---------------------------------------------------------------------------
__global__ __launch_bounds__(64) void k2_gates(
        const float* __restrict__ pooled,
        const float* __restrict__ w1, const float* __restrict__ b1,
        const float* __restrict__ wk, const float* __restrict__ wi,
        const float* __restrict__ wo, const float* __restrict__ wn,
        float* __restrict__ kr, float* __restrict__ inc,
        float* __restrict__ outc, float* __restrict__ nums)
{
    int b = blockIdx.x, lane = threadIdx.x;
    float pc[4];
#pragma unroll
    for (int j = 0; j < 4; ++j)
        pc[j] = pooled[b * CI + lane + 64 * j];
    float h[SQD];
#pragma unroll
    for (int s = 0; s < SQD; ++s) {
        float ps = 0.f;
#pragma unroll
        for (int j = 0; j < 4; ++j)
            ps += pc[j] * w1[(lane + 64 * j) * SQD + s];
        for (int m = 1; m <= 32; m <<= 1) ps += __shfl_xor(ps, m);
        float z = ps + b1[s];
        h[s] = 0.5f * z * (1.0f + erff(z * 0.70710678118654752f));
    }
    if (lane < KW) {
        float a = 0.f;
#pragma unroll
        for (int s = 0; s < SQD; ++s) a += h[s] * wk[s * KW + lane];
        kr[b * 8 + lane] = 1.0f / (1.0f + expf(-a));
    }
    if (lane < NW) {
        float e[NW]; float mx = -1e30f;
#pragma unroll
        for (int n = 0; n < NW; ++n) {
            float a = 0.f;
#pragma unroll
            for (int s = 0; s < SQD; ++s) a += h[s] * wn[s * NW + n];
            e[n] = a; mx = fmaxf(mx, a);
        }
        float den = 0.f;
#pragma unroll
        for (int n = 0; n < NW; ++n) den += expf(e[n] - mx);
        nums[b * NW + lane] = expf(e[lane] - mx) / den;
    }
#pragma unroll
    for (int j = 0; j < 4; ++j) {
        int c = lane + 64 * j;
        float a = 0.f, o2 = 0.f;
#pragma unroll
        for (int s = 0; s < SQD; ++s) {
            a  += h[s] * wi[s * CI + c];
            o2 += h[s] * wo[s * CO + c];
        }
        inc[b * CI + c]  = 1.0f / (1.0f + expf(-a));
        outc[b * CO + c] = 1.0f / (1.0f + expf(-o2));
    }
}

// ---------------------------------------------------------------------------
// k3: per-sample mixed weights, MFMA layout W2[b][k*8+ic][o][i%32] bf16.
// ---------------------------------------------------------------------------
__global__ __launch_bounds__(256) void k3_wgen(
        const float* __restrict__ cw,
        const float* __restrict__ kr, const float* __restrict__ inc,
        const float* __restrict__ outc, const float* __restrict__ nums,
        unsigned short* __restrict__ W2) {
    __shared__ float s_nums[B_][NW];
    __shared__ float s_kr[B_][KW];
    __shared__ float s_inc[B_][32];
    __shared__ float s_outc[B_][8];
    int t = threadIdx.x;
    int ic = blockIdx.x & 7, o0 = (blockIdx.x >> 3) * 8;
    s_nums[t >> 3][t & 7] = nums[t];
    if (t < B_ * KW) s_kr[t / KW][t % KW] = kr[(t / KW) * 8 + (t % KW)];
    for (int u = t; u < 32 * 32; u += 256) {
        int bb = u >> 5, ii = u & 31;
        s_inc[bb][ii] = inc[bb * CI + ic * 32 + ii];
    }
    for (int u = t; u < 32 * 8; u += 256) {
        int bb = u >> 3, oo = u & 7;
        s_outc[bb][oo] = outc[bb * CO + o0 + oo];
    }
    __syncthreads();
    int ii = t & 31, oo = t >> 5;
    int o = o0 + oo, i = ic * 32 + ii;
    float cwv[KW][NW];
    const float* p = cw + ((size_t)(o * CI + i)) * (KW * NW);
#pragma unroll
    for (int k = 0; k < KW; ++k)
#pragma unroll
        for (int n = 0; n < NW; ++n) cwv[k][n] = p[k * NW + n];
    for (int bb = 0; bb < B_; ++bb) {
        float gio = s_inc[bb][ii] * s_outc[bb][oo];
#pragma unroll
        for (int k = 0; k < KW; ++k) {
            float sk = 0.f;
#pragma unroll
            for (int n = 0; n < NW; ++n) sk += s_nums[bb][n] * cwv[k][n];
            float w = s_kr[bb][k] * gio * sk;
            W2[(((size_t)(bb * KW + k) * 8 + ic) * CO + o) * 32 + ii] = f2bf(w);
        }
    }
}

// ---------------------------------------------------------------------------
// k4: fused transpose + per-sample im2col GEMM (16x16x32 bf16 MFMA).
//     r9 structure with a 64-l tile for TLP:
//     Block = 256 o x 64 l, 256 threads = 4 o-split waves (A-red 1),
//     wave = 64o x 64l, acc[4][4] + 2-deep pipeline.
//     LDS xs[70][264] bf16 = 37 KB; __launch_bounds__(256,3) ->
//     3 blocks/CU = 12 waves/CU = 3 waves/SIMD (1.5x r9's TLP).
//     Per-CU MFMA/LDS walls are tile-invariant; only latency hiding
//     improves. PITCH 264 (measured-best banks). No nt (r15 refuted).
//     Grid 2048 = 32 samples x 64 l-tiles, XCD-bijective swizzle.
// ---------------------------------------------------------------------------
__global__ __launch_bounds__(256, 3) void k4_conv(
        const float* __restrict__ x,             // fp32 [B][CI][L]
        const unsigned short* __restrict__ W2,   // bf16 [B][56][CO][32]
        float* __restrict__ out) {               // [B][CO][L]
    __shared__ __align__(16) unsigned short xs[70 * PITCH];
    int bid = blockIdx.x;
    int wg  = (bid & 7) * 256 + (bid >> 3);      // XCD-bijective (2048%8==0)
    int b = wg >> 6, l0 = (wg & 63) * 64;
    int t = threadIdx.x;
    const float* xb = x + (size_t)b * CI * L_;

    // ---- main staging: rows 3..66 (l = l0..l0+63), i linear ----
    {
        int u = t >> 3;                          // 16B unit 0..31 = i 8u..8u+7
        int lam = t & 7;
        int i0 = u * 8;
#pragma unroll
        for (int it = 0; it < 2; ++it) {
            int ch = lam + 8 * it;               // l-chunk 0..15 (4 l each)
            const float* src = xb + (size_t)i0 * L_ + l0 + ch * 4;
            float4 f[8];
#pragma unroll
            for (int e = 0; e < 8; ++e)
                f[e] = *(const float4*)(src + (size_t)e * L_);
#pragma unroll
            for (int j = 0; j < 4; ++j) {
                int r = ch * 4 + j + 3;
                uint2 a = pack4bf(f[0].x * 0.f + (&f[0].x)[j], (&f[1].x)[j],
                                  (&f[2].x)[j], (&f[3].x)[j]);
                uint2 c = pack4bf((&f[4].x)[j], (&f[5].x)[j],
                                  (&f[6].x)[j], (&f[7].x)[j]);
                uint4 w; w.x = a.x; w.y = a.y; w.z = c.x; w.w = c.y;
                *(uint4*)(xs + r * PITCH + u * 8) = w;
            }
        }
    }
    // ---- halo: rows 0..2 (gl=l0-3..l0-1), 67..69 (gl=l0+64..l0+66) ----
    if (t < 192) {
        int h = t >> 5, u = t & 31;
        int r = (h < 3) ? h : (64 + h);
        int gl = l0 - 3 + r;
        bool ok = (gl >= 0 && gl < L_);
        float f[8];
#pragma unroll
        for (int e = 0; e < 8; ++e)
            f[e] = ok ? xb[(size_t)(u * 8 + e) * L_ + gl] : 0.f;
        uint2 a = pack4bf(f[0], f[1], f[2], f[3]);
        uint2 c = pack4bf(f[4], f[5], f[6], f[7]);
        uint4 w; w.x = a.x; w.y = a.y; w.z = c.x; w.w = c.y;
        *(uint4*)(xs + r * PITCH + u * 8) = w;
    }
    __syncthreads();

    int lane = t & 63, wid = t >> 6;
    int o_base = wid * 64;                       // 4 o-split waves x 64 o
    int ml = lane & 15, kg = lane >> 4;

    f32x4 acc[4][4];
#pragma unroll
    for (int a = 0; a < 4; ++a)
#pragma unroll
        for (int c = 0; c < 4; ++c) acc[a][c] = (f32x4){0.f, 0.f, 0.f, 0.f};

    const unsigned short* wA = W2 + (size_t)b * (56 * CO * 32)
                               + (o_base + ml) * 32 + kg * 8;
    const unsigned short* xB = xs + (size_t)ml * PITCH + kg * 8;

    auto LOADF = [&](bf16x8 (&AF)[4], bf16x8 (&BF)[4], int S) {
        int k_ = S >> 3, icc_ = S & 7;
#pragma unroll
        for (int mt = 0; mt < 4; ++mt)
            AF[mt] = *(const bf16x8*)(wA + (size_t)S * (CO * 32) + mt * 16 * 32);
#pragma unroll
        for (int nt = 0; nt < 4; ++nt)
            BF[nt] = *(const bf16x8*)(xB + (nt * 16 + k_) * PITCH + icc_ * 32);
    };
    auto DOMFMA = [&](bf16x8 (&AF)[4], bf16x8 (&BF)[4]) {
        __builtin_amdgcn_s_setprio(1);
#pragma unroll
        for (int mt = 0; mt < 4; ++mt)
#pragma unroll
            for (int nt = 0; nt < 4; ++nt)
                acc[mt][nt] = __builtin_amdgcn_mfma_f32_16x16x32_bf16(
                    AF[mt], BF[nt], acc[mt][nt], 0, 0, 0);
        __builtin_amdgcn_s_setprio(0);
    };

    bf16x8 afA[4], bfA[4], afB[4], bfB[4];
    LOADF(afA, bfA, 0);
    for (int s = 0; s < 56; s += 2) {
        LOADF(afB, bfB, s + 1);
        DOMFMA(afA, bfA);
        if (s + 2 < 56) LOADF(afA, bfA, s + 2);
        DOMFMA(afB, bfB);
    }

    // epilogue: D row(o)=(lane>>4)*4+q, col(l)=lane&15
#pragma unroll
    for (int mt = 0; mt < 4; ++mt) {
        int o = o_base + mt * 16 + kg * 4;
#pragma unroll
        for (int nt = 0; nt < 4; ++nt) {
            int l = l0 + nt * 16 + ml;
            float* po = out + ((size_t)(b * CO + o)) * L_ + l;
#pragma unroll
            for (int q = 0; q < 4; ++q)
                po[(size_t)q * L_] = acc[mt][nt][q];
        }
    }
}

// ---------------------------------------------------------------------------
extern "C" void kernel_launch(void* const* d_in, const int* in_sizes, int n_in,
                              void* d_out, int out_size, void* d_ws, size_t ws_size,
                              hipStream_t stream) {
    const float* x  = (const float*)d_in[0];
    const float* cw = (const float*)d_in[1];
    const float* w1 = (const float*)d_in[2];
    const float* b1 = (const float*)d_in[3];
    const float* wk = (const float*)d_in[4];
    const float* wi = (const float*)d_in[5];
    const float* wo = (const float*)d_in[6];
    const float* wn = (const float*)d_in[7];
    float* out = (float*)d_out;

    char* ws = (char*)d_ws;
    unsigned short* W2 = (unsigned short*)(ws + 0);          // 29360128 B
    float* pooled = (float*)(ws + 29360128);
    float* kr     = (float*)(ws + 29392896);
    float* inc    = (float*)(ws + 29393920);
    float* outc   = (float*)(ws + 29426688);
    float* nums   = (float*)(ws + 29459456);

    k1_mean<<<B_ * CI, 256, 0, stream>>>(x, pooled);
    k2_gates<<<B_, 64, 0, stream>>>(pooled, w1, b1, wk, wi, wo, wn,
                                    kr, inc, outc, nums);
    k3_wgen<<<256, 256, 0, stream>>>(cw, kr, inc, outc, nums, W2);
    k4_conv<<<2048, 256, 0, stream>>>(x, W2, out);
}

// Round 17
// 166.533 us; speedup vs baseline: 1.1312x; 1.1312x over previous
//
#include <hip/hip_runtime.h>
#include <hip/hip_bf16.h>
#include <math.h>

#define B_   32
#define CI   256
#define CO   256
#define KW   7
#define NW   8
#define SQD  8
#define L_   4096
#define PITCH 264

typedef __attribute__((ext_vector_type(8))) __bf16 bf16x8;
typedef __attribute__((ext_vector_type(4))) __bf16 bf16x4;
typedef __attribute__((ext_vector_type(4))) float  f32x4;

static __device__ __forceinline__ unsigned short f2bf(float f) {
    unsigned int u = __builtin_bit_cast(unsigned int, f);
    u += 0x7FFFu + ((u >> 16) & 1u);
    return (unsigned short)(u >> 16);
}
// native-cast pack: compiler emits v_cvt_pk_bf16_f32
static __device__ __forceinline__ uint2 pack4bf(float a, float b, float c, float d) {
    bf16x4 v;
    v[0] = (__bf16)a; v[1] = (__bf16)b; v[2] = (__bf16)c; v[3] = (__bf16)d;
    return __builtin_bit_cast(uint2, v);
}

// ---------------------------------------------------------------------------
// k1: mean over L (deterministic). One block per (b,i) row.
// ---------------------------------------------------------------------------
__global__ __launch_bounds__(256) void k1_mean(
        const float* __restrict__ x, float* __restrict__ pooled) {
    int row = blockIdx.x;                       // b*CI + i
    const float* p = x + (size_t)row * L_;
    int t = threadIdx.x;
    float s = 0.f;
#pragma unroll
    for (int it = 0; it < 4; ++it) {
        float4 v = *(const float4*)(p + (size_t)(t + 256 * it) * 4);
        s += v.x + v.y + v.z + v.w;
    }
    for (int m = 1; m <= 32; m <<= 1) s += __shfl_xor(s, m);
    __shared__ float wsum[4];
    if ((t & 63) == 0) wsum[t >> 6] = s;
    __syncthreads();
    if (t == 0)
        pooled[row] = (wsum[0] + wsum[1] + wsum[2] + wsum[3]) * (1.0f / L_);
}

// ---------------------------------------------------------------------------
// k2: squeeze net + gates. one block (1 wave) per sample.
// ---------------------------------------------------------------------------
__global__ __launch_bounds__(64) void k2_gates(
        const float* __restrict__ pooled,
        const float* __restrict__ w1, const float* __restrict__ b1,
        const float* __restrict__ wk, const float* __restrict__ wi,
        const float* __restrict__ wo, const float* __restrict__ wn,
        float* __restrict__ kr, float* __restrict__ inc,
        float* __restrict__ outc, float* __restrict__ nums)
{
    int b = blockIdx.x, lane = threadIdx.x;
    float pc[4];
#pragma unroll
    for (int j = 0; j < 4; ++j)
        pc[j] = pooled[b * CI + lane + 64 * j];
    float h[SQD];
#pragma unroll
    for (int s = 0; s < SQD; ++s) {
        float ps = 0.f;
#pragma unroll
        for (int j = 0; j < 4; ++j)
            ps += pc[j] * w1[(lane + 64 * j) * SQD + s];
        for (int m = 1; m <= 32; m <<= 1) ps += __shfl_xor(ps, m);
        float z = ps + b1[s];
        h[s] = 0.5f * z * (1.0f + erff(z * 0.70710678118654752f));
    }
    if (lane < KW) {
        float a = 0.f;
#pragma unroll
        for (int s = 0; s < SQD; ++s) a += h[s] * wk[s * KW + lane];
        kr[b * 8 + lane] = 1.0f / (1.0f + expf(-a));
    }
    if (lane < NW) {
        float e[NW]; float mx = -1e30f;
#pragma unroll
        for (int n = 0; n < NW; ++n) {
            float a = 0.f;
#pragma unroll
            for (int s = 0; s < SQD; ++s) a += h[s] * wn[s * NW + n];
            e[n] = a; mx = fmaxf(mx, a);
        }
        float den = 0.f;
#pragma unroll
        for (int n = 0; n < NW; ++n) den += expf(e[n] - mx);
        nums[b * NW + lane] = expf(e[lane] - mx) / den;
    }
#pragma unroll
    for (int j = 0; j < 4; ++j) {
        int c = lane + 64 * j;
        float a = 0.f, o2 = 0.f;
#pragma unroll
        for (int s = 0; s < SQD; ++s) {
            a  += h[s] * wi[s * CI + c];
            o2 += h[s] * wo[s * CO + c];
        }
        inc[b * CI + c]  = 1.0f / (1.0f + expf(-a));
        outc[b * CO + c] = 1.0f / (1.0f + expf(-o2));
    }
}

// ---------------------------------------------------------------------------
// k3: per-sample mixed weights, MFMA layout W2[b][k*8+ic][o][i%32] bf16.
// ---------------------------------------------------------------------------
__global__ __launch_bounds__(256) void k3_wgen(
        const float* __restrict__ cw,
        const float* __restrict__ kr, const float* __restrict__ inc,
        const float* __restrict__ outc, const float* __restrict__ nums,
        unsigned short* __restrict__ W2) {
    __shared__ float s_nums[B_][NW];
    __shared__ float s_kr[B_][KW];
    __shared__ float s_inc[B_][32];
    __shared__ float s_outc[B_][8];
    int t = threadIdx.x;
    int ic = blockIdx.x & 7, o0 = (blockIdx.x >> 3) * 8;
    s_nums[t >> 3][t & 7] = nums[t];
    if (t < B_ * KW) s_kr[t / KW][t % KW] = kr[(t / KW) * 8 + (t % KW)];
    for (int u = t; u < 32 * 32; u += 256) {
        int bb = u >> 5, ii = u & 31;
        s_inc[bb][ii] = inc[bb * CI + ic * 32 + ii];
    }
    for (int u = t; u < 32 * 8; u += 256) {
        int bb = u >> 3, oo = u & 7;
        s_outc[bb][oo] = outc[bb * CO + o0 + oo];
    }
    __syncthreads();
    int ii = t & 31, oo = t >> 5;
    int o = o0 + oo, i = ic * 32 + ii;
    float cwv[KW][NW];
    const float* p = cw + ((size_t)(o * CI + i)) * (KW * NW);
#pragma unroll
    for (int k = 0; k < KW; ++k)
#pragma unroll
        for (int n = 0; n < NW; ++n) cwv[k][n] = p[k * NW + n];
    for (int bb = 0; bb < B_; ++bb) {
        float gio = s_inc[bb][ii] * s_outc[bb][oo];
#pragma unroll
        for (int k = 0; k < KW; ++k) {
            float sk = 0.f;
#pragma unroll
            for (int n = 0; n < NW; ++n) sk += s_nums[bb][n] * cwv[k][n];
            float w = s_kr[bb][k] * gio * sk;
            W2[(((size_t)(bb * KW + k) * 8 + ic) * CO + o) * 32 + ii] = f2bf(w);
        }
    }
}

// ---------------------------------------------------------------------------
// k4: fused transpose + per-sample im2col GEMM (16x16x32 bf16 MFMA).
//     EXACT r9 geometry (best, 123 us): block = 256o x 128l, 256 threads
//     = 4 o-split waves (A-red 1), wave = 64o x 128l, acc[4][8],
//     PITCH 264, 2 blocks/CU.
//     Change: K-loop restructured into 8 fine-grained mini-phases/step,
//     each {1 ds_read (B of s+1) + (j<4: 1 global A of s+1) + 4 MFMA of
//     col j}, pinned with sched_group_barrier (DS=0x100, VMEM=0x20,
//     MFMA=0x8) so the emitted stream alternates LDS/matrix pipes at
//     ~77-cyc granularity instead of 620-cyc bursts. Every load's
//     consumer is one full step (~620 cyc) downstream.
// ---------------------------------------------------------------------------
__global__ __launch_bounds__(256, 2) void k4_conv(
        const float* __restrict__ x,             // fp32 [B][CI][L]
        const unsigned short* __restrict__ W2,   // bf16 [B][56][CO][32]
        float* __restrict__ out) {               // [B][CO][L]
    __shared__ __align__(16) unsigned short xs[134 * PITCH];
    int bid = blockIdx.x;
    int wg  = (bid & 7) * 128 + (bid >> 3);      // XCD-bijective (1024%8==0)
    int b = wg >> 5, l0 = (wg & 31) * 128;
    int t = threadIdx.x;
    const float* xb = x + (size_t)b * CI * L_;

    // ---- main staging: rows 3..130 (l = l0..l0+127), i linear ----
    {
        int u = t >> 3;                          // 16B unit 0..31 = i 8u..8u+7
        int lam = t & 7;
        int i0 = u * 8;
#pragma unroll
        for (int it = 0; it < 4; ++it) {
            int ch = lam + 8 * it;               // l-chunk 0..31 (4 l each)
            const float* src = xb + (size_t)i0 * L_ + l0 + ch * 4;
            float4 f[8];
#pragma unroll
            for (int e = 0; e < 8; ++e)
                f[e] = *(const float4*)(src + (size_t)e * L_);
#pragma unroll
            for (int j = 0; j < 4; ++j) {
                int r = ch * 4 + j + 3;
                uint2 a = pack4bf((&f[0].x)[j], (&f[1].x)[j], (&f[2].x)[j], (&f[3].x)[j]);
                uint2 c = pack4bf((&f[4].x)[j], (&f[5].x)[j], (&f[6].x)[j], (&f[7].x)[j]);
                uint4 w; w.x = a.x; w.y = a.y; w.z = c.x; w.w = c.y;
                *(uint4*)(xs + r * PITCH + u * 8) = w;
            }
        }
    }
    // ---- halo: rows 0..2 (gl=l0-3..l0-1), 131..133 (gl=l0+128..l0+130) ----
    if (t < 192) {
        int h = t >> 5, u = t & 31;
        int r = (h < 3) ? h : (128 + h);
        int gl = l0 - 3 + r;
        bool ok = (gl >= 0 && gl < L_);
        float f[8];
#pragma unroll
        for (int e = 0; e < 8; ++e)
            f[e] = ok ? xb[(size_t)(u * 8 + e) * L_ + gl] : 0.f;
        uint2 a = pack4bf(f[0], f[1], f[2], f[3]);
        uint2 c = pack4bf(f[4], f[5], f[6], f[7]);
        uint4 w; w.x = a.x; w.y = a.y; w.z = c.x; w.w = c.y;
        *(uint4*)(xs + r * PITCH + u * 8) = w;
    }
    __syncthreads();

    int lane = t & 63, wid = t >> 6;
    int o_base = wid * 64;                       // 4 o-split waves x 64 o
    int ml = lane & 15, kg = lane >> 4;

    f32x4 acc[4][8];
#pragma unroll
    for (int a = 0; a < 4; ++a)
#pragma unroll
        for (int c = 0; c < 8; ++c) acc[a][c] = (f32x4){0.f, 0.f, 0.f, 0.f};

    const unsigned short* wA = W2 + (size_t)b * (56 * CO * 32)
                               + (o_base + ml) * 32 + kg * 8;
    const unsigned short* xB = xs + (size_t)ml * PITCH + kg * 8;

    bf16x8 afA[4], bfA[8], afB[4], bfB[8];

    // prologue: step 0 into set A
#pragma unroll
    for (int j = 0; j < 8; ++j)
        bfA[j] = *(const bf16x8*)(xB + (j * 16) * PITCH);
#pragma unroll
    for (int mt = 0; mt < 4; ++mt)
        afA[mt] = *(const bf16x8*)(wA + mt * 16 * 32);

    // one K-step: MFMA on (AFc,BFc), prefetch step sn into (AFn,BFn),
    // interleaved 8 mini-phases with sched_group_barrier pinning.
    auto STEP = [&](bf16x8 (&AFc)[4], bf16x8 (&BFc)[8],
                    bf16x8 (&AFn)[4], bf16x8 (&BFn)[8],
                    int sn, bool pf) {
        int k_ = sn >> 3, icc_ = sn & 7;
#pragma unroll
        for (int j = 0; j < 8; ++j) {
            if (pf) {
                BFn[j] = *(const bf16x8*)(xB + (j * 16 + k_) * PITCH + icc_ * 32);
                if (j < 4)
                    AFn[j] = *(const bf16x8*)(wA + (size_t)sn * (CO * 32)
                                              + j * 16 * 32);
            }
#pragma unroll
            for (int mt = 0; mt < 4; ++mt)
                acc[mt][j] = __builtin_amdgcn_mfma_f32_16x16x32_bf16(
                    AFc[mt], BFc[j], acc[mt][j], 0, 0, 0);
            if (pf) {
                __builtin_amdgcn_sched_group_barrier(0x100, 1, 0);  // 1 ds_read
                if (j < 4)
                    __builtin_amdgcn_sched_group_barrier(0x020, 1, 0); // 1 vmem rd
            }
            __builtin_amdgcn_sched_group_barrier(0x008, 4, 0);      // 4 MFMA
        }
    };

    for (int s = 0; s < 54; s += 2) {
        STEP(afA, bfA, afB, bfB, s + 1, true);
        STEP(afB, bfB, afA, bfA, s + 2, true);
    }
    STEP(afA, bfA, afB, bfB, 55, true);   // compute step 54, prefetch 55
    STEP(afB, bfB, afA, bfA, 0, false);   // compute step 55

    // epilogue: D row(o)=(lane>>4)*4+q, col(l)=lane&15
#pragma unroll
    for (int mt = 0; mt < 4; ++mt) {
        int o = o_base + mt * 16 + kg * 4;
#pragma unroll
        for (int nt = 0; nt < 8; ++nt) {
            int l = l0 + nt * 16 + ml;
            float* po = out + ((size_t)(b * CO + o)) * L_ + l;
#pragma unroll
            for (int q = 0; q < 4; ++q)
                po[(size_t)q * L_] = acc[mt][nt][q];
        }
    }
}

// ---------------------------------------------------------------------------
extern "C" void kernel_launch(void* const* d_in, const int* in_sizes, int n_in,
                              void* d_out, int out_size, void* d_ws, size_t ws_size,
                              hipStream_t stream) {
    const float* x  = (const float*)d_in[0];
    const float* cw = (const float*)d_in[1];
    const float* w1 = (const float*)d_in[2];
    const float* b1 = (const float*)d_in[3];
    const float* wk = (const float*)d_in[4];
    const float* wi = (const float*)d_in[5];
    const float* wo = (const float*)d_in[6];
    const float* wn = (const float*)d_in[7];
    float* out = (float*)d_out;

    char* ws = (char*)d_ws;
    unsigned short* W2 = (unsigned short*)(ws + 0);          // 29360128 B
    float* pooled = (float*)(ws + 29360128);
    float* kr     = (float*)(ws + 29392896);
    float* inc    = (float*)(ws + 29393920);
    float* outc   = (float*)(ws + 29426688);
    float* nums   = (float*)(ws + 29459456);

    k1_mean<<<B_ * CI, 256, 0, stream>>>(x, pooled);
    k2_gates<<<B_, 64, 0, stream>>>(pooled, w1, b1, wk, wi, wo, wn,
                                    kr, inc, outc, nums);
    k3_wgen<<<256, 256, 0, stream>>>(cw, kr, inc, outc, nums, W2);
    k4_conv<<<1024, 256, 0, stream>>>(x, W2, out);
}